// Round 1
// 134.309 us; speedup vs baseline: 1.0191x; 1.0191x over previous
//
#include <hip/hip_runtime.h>
#include <hip/hip_bf16.h>

// Problem constants
constexpr int Bb  = 8;
constexpr int Ss  = 2048;
constexpr int Ee  = 128;
constexpr int Hh  = 8;
constexpr int HSs = 16;
constexpr int QKVSZ = Bb * Hh * Ss * HSs;  // 2,097,152 elements per tensor

typedef _Float16 f16;
typedef __attribute__((ext_vector_type(8)))  _Float16 f16x8;   // 8 f16 = 4 VGPRs
typedef __attribute__((ext_vector_type(16))) float f32x16;

constexpr float QSCALE = 5.770780163555854f;  // 4 * log2(e); folded into stored k

// RTZ packed fp32x2 -> fp16x2
__device__ __forceinline__ unsigned pack_rtz(float lo, float hi) {
    union { __fp16 __attribute__((ext_vector_type(2))) h; unsigned u; } c;
    c.h = __builtin_amdgcn_cvt_pkrtz(lo, hi);
    return c.u;
}
// RNE pair pack
__device__ __forceinline__ unsigned pack_rne(float lo, float hi) {
    union { __attribute__((ext_vector_type(2))) _Float16 h; unsigned u; } c;
    c.h[0] = (f16)lo; c.h[1] = (f16)hi;
    return c.u;
}

// max of 16 floats, max3-friendly groupings (ISel fuses fmax(fmax(a,b),c) -> v_max3_f32)
__device__ __forceinline__ float vmax16(const f32x16& v) {
    float a = fmaxf(fmaxf(v[0],  v[1]),  v[2]);
    float b = fmaxf(fmaxf(v[3],  v[4]),  v[5]);
    float c = fmaxf(fmaxf(v[6],  v[7]),  v[8]);
    float d = fmaxf(fmaxf(v[9],  v[10]), v[11]);
    float e = fmaxf(fmaxf(v[12], v[13]), v[14]);
    float g = fmaxf(fmaxf(a, b), c);
    float h = fmaxf(fmaxf(d, e), v[15]);
    return fmaxf(g, h);
}

// ---------------------------------------------------------------------------
// prep_w: one-time fp32 -> f16 of all weights. wh = [wq|wk|wv|wp], 16K each.
// ---------------------------------------------------------------------------
__global__ __launch_bounds__(256) void prep_w(
    const float* __restrict__ Wq, const float* __restrict__ Wk,
    const float* __restrict__ Wv, const float* __restrict__ Wp,
    f16* __restrict__ wh)
{
    int i = (blockIdx.x * 256 + threadIdx.x) * 4;
    const float* src = (i < 16384) ? (Wq + i)
                     : (i < 32768) ? (Wk + i - 16384)
                     : (i < 49152) ? (Wv + i - 32768) : (Wp + i - 49152);
    float4 v = *(const float4*)src;
    union { f16 h[4]; uint2 u; } c;
    c.h[0] = (f16)v.x; c.h[1] = (f16)v.y; c.h[2] = (f16)v.z; c.h[3] = (f16)v.w;
    *(uint2*)(wh + i) = c.u;
}

// ---------------------------------------------------------------------------
// Kernel A: FUSED Q/K/V projection. Grid 512, 4 waves. X staged fp32->f16 via
// LDS ONCE, A-frags loaded once, then 3 x 8 MFMA (q,k,v) reusing them.
// k scaled by QSCALE. v written in A-FRAG ORDER with the key-slot PERMUTATION
// matching the QK^T C-layout, so attn's P feeds PV with NO cross-lane exchange:
//   in-chunk key p = 4h' + a + 8b  ->  va-group p>>4, lane-half h'=(p>>2)&1,
//   element j = 4*((p>>3)&1) + (p&3).
// Pad rows m=16..31 (m==16 -> 1.0 ones-row for the l-accumulator trick).
// 32x32x16 layouts: A[m=lane&31][k=8h+j], B[k=8h+j][n=lane&31],
// C/D[row=(r&3)+8(r>>2)+4h][col=lane&31].
// ---------------------------------------------------------------------------
__global__ __launch_bounds__(256) void qkv_kernel(
    const float* __restrict__ x, const f16* __restrict__ wh,
    f16* __restrict__ qo, f16* __restrict__ ko, f16* __restrict__ vo)
{
    constexpr int LDW = 136;                      // padded row (f16), b128-aligned
    __shared__ __align__(16) f16 Xs[32 * LDW];    // 8.7 KB

    const int rowbase = blockIdx.x * 32;

    // stage X tile (32 x 128) fp32 -> f16, coalesced float4 reads (ONCE)
    for (int idx = threadIdx.x; idx < 32 * 32; idx += 256) {
        const int r = idx >> 5, cp = idx & 31;
        float4 v = *(const float4*)(x + (size_t)(rowbase + r) * Ee + cp * 4);
        union { f16 h[4]; uint2 u; } cv;
        cv.h[0] = (f16)v.x; cv.h[1] = (f16)v.y; cv.h[2] = (f16)v.z; cv.h[3] = (f16)v.w;
        *(uint2*)&Xs[r * LDW + cp * 4] = cv.u;
    }
    __syncthreads();

    const int wv_ = threadIdx.x >> 6, lane = threadIdx.x & 63;
    const int h = lane >> 5, n31 = lane & 31;

    f16x8 A[8];
#pragma unroll
    for (int t = 0; t < 8; ++t)
        A[t] = *(const f16x8*)&Xs[n31 * LDW + 16 * t + 8 * h];

    const int c = wv_ * 32 + n31;                 // channel 0..127 = head*16+d
    const int b = rowbase >> 11;
    const int s0 = rowbase & 2047;
    const int head = c >> 4, d = c & 15;
    const int bh = b * Hh + head;
    const int it = s0 >> 6, g0 = (s0 >> 4) & 3;

#pragma unroll
    for (int mat = 0; mat < 3; ++mat) {
        const f16* wr = wh + mat * 16384 + (size_t)c * Ee + 8 * h;
        f32x16 acc = {};
#pragma unroll
        for (int t = 0; t < 8; ++t)
            acc = __builtin_amdgcn_mfma_f32_32x32x16_f16(A[t], *(const f16x8*)(wr + 16 * t), acc, 0, 0, 0);

        if (mat < 2) {
            f16* dst = (mat == 0) ? qo : ko;
            const float scale = (mat == 1) ? QSCALE : 1.f;
#pragma unroll
            for (int r = 0; r < 16; ++r) {
                const int s = s0 + (r & 3) + 8 * (r >> 2) + 4 * h;
                dst[((size_t)bh * Ss + s) * HSs + d] = (f16)(acc[r] * scale);
            }
        } else {
            f16* vb = vo + (size_t)bh * 65536 + it * 2048;
#pragma unroll
            for (int rq = 0; rq < 4; ++rq) {
                union { f16 hv[4]; uint2 u; } pk4;
#pragma unroll
                for (int i = 0; i < 4; ++i) pk4.hv[i] = (f16)acc[4 * rq + i];
                // permuted k-slot placement: h' = h, b' = rq&1, j = 4*b' + a
                *(uint2*)(vb + (g0 + (rq >> 1)) * 512 + (d + 32 * h) * 8 + 4 * (rq & 1)) = pk4.u;
            }
        }
    }

    // pad rows m=16..31 for this block's two 16-key groups, all 8 heads:
    // m==16 -> 1.0 (l-accumulator row), else 0. All k-slots equal -> permutation-safe.
    for (int i = threadIdx.x; i < 512; i += 256) {
        const int gp = i >> 8, hd = (i >> 5) & 7, cc = i & 31;
        const int lanep = (cc < 16) ? 16 + cc : 32 + cc;
        const unsigned one2 = 0x3C003C00u;
        uint4 val = ((cc & 15) == 0) ? (uint4){one2, one2, one2, one2}
                                     : (uint4){0, 0, 0, 0};
        *(uint4*)(vo + (size_t)(b * Hh + hd) * 65536 + it * 2048
                  + (g0 + gp) * 512 + lanep * 8) = val;
    }
}

// ---------------------------------------------------------------------------
// Kernel B: MFMA flash attention, NO LDS, NO BARRIERS, NO CROSS-LANE P
// EXCHANGE. 4096 blocks x 1 wave; wave owns 32 queries, streams 64-key chunks.
// V's key-slot permutation makes B1..B4 pure register renames of exp(st).
// Running max folded into the QK^T MFMA C-operand (cinit = -m); deferred
// rescale with THR=8 (p <= 256, f16-safe) via wave-uniform __any branch.
// Next-chunk operands loaded in-place right after last use (one-iter distance).
// XCD swizzle: bh = (blk&7)*8 + blk>>9 -> each bh's 64 blocks on one XCD.
// ---------------------------------------------------------------------------
__global__ __launch_bounds__(64, 4) void attn_kernel(
    const f16* __restrict__ qg, const f16* __restrict__ kg,
    const f16* __restrict__ vg, f16* __restrict__ og)
{
    const int blk  = blockIdx.x;                   // 4096
    const int bh   = (blk & 7) * 8 + (blk >> 9);   // XCD-local bh groups
    const int qblk = (blk >> 3) & 63;
    const int lane = threadIdx.x;
    const int h    = lane >> 5;
    const int q31  = lane & 31;
    const int qbase = qblk * 32;

    // Q B-frag (QSCALE folded into k)
    const f16x8 qf = *(const f16x8*)(qg + ((size_t)bh * Ss + qbase + q31) * HSs + 8 * h);

    // per-lane streaming pointers (16B/lane contiguous, coalesced per wave)
    const f16* pk = kg + (size_t)bh * Ss * HSs + q31 * 16 + 8 * h;
    const f16* pv = vg + (size_t)bh * 65536 + lane * 8;

    // current-chunk operands
    f16x8 ka0 = *(const f16x8*)pk;
    f16x8 ka1 = *(const f16x8*)(pk + 512);
    f16x8 va0 = *(const f16x8*)(pv);
    f16x8 va1 = *(const f16x8*)(pv + 512);
    f16x8 va2 = *(const f16x8*)(pv + 1024);
    f16x8 va3 = *(const f16x8*)(pv + 1536);

    f32x16 acc = {};
    f32x16 cinit = {};                 // broadcast -m; st = s - m straight from MFMA

    constexpr int NIT = Ss / 64;
    for (int it = 0; it < NIT; ++it) {
        // S^T - m = K x Q^T + cinit for key groups 0..31, 32..63
        f32x16 st0 = __builtin_amdgcn_mfma_f32_32x32x16_f16(ka0, qf, cinit, 0, 0, 0);
        f32x16 st1 = __builtin_amdgcn_mfma_f32_32x32x16_f16(ka1, qf, cinit, 0, 0, 0);

        // K operands dead: load next chunk in-place (used next iteration)
        if (it + 1 < NIT) {
            pk += 1024;
            ka0 = *(const f16x8*)pk;
            ka1 = *(const f16x8*)(pk + 512);
        }

        // chunk max relative to m (max3 tree + one xor32)
        float mx = fmaxf(vmax16(st0), vmax16(st1));
        mx = fmaxf(mx, __shfl_xor(mx, 32, 64));

        // deferred rescale: only when some query grew past m + 8
        if (__any(mx > 8.f)) {
            const float delta = fmaxf(mx, 0.f);
            const float corr  = __builtin_amdgcn_exp2f(-delta);
#pragma unroll
            for (int r = 0; r < 9; ++r) acc[r] *= corr;   // d<16 regs + l in acc[8]
#pragma unroll
            for (int t = 0; t < 16; ++t) { st0[t] -= delta; st1[t] -= delta; }
#pragma unroll
            for (int r = 0; r < 16; ++r) cinit[r] -= delta;
        }

        // p = exp2(st) packed to f16; key-slot permutation => direct renames
        union { unsigned u[4]; f16x8 v; } B1, B2, B3, B4;
#pragma unroll
        for (int r = 0; r < 4; ++r) {
            B1.u[r] = pack_rtz(__builtin_amdgcn_exp2f(st0[2 * r]),
                               __builtin_amdgcn_exp2f(st0[2 * r + 1]));
            B2.u[r] = pack_rtz(__builtin_amdgcn_exp2f(st0[8 + 2 * r]),
                               __builtin_amdgcn_exp2f(st0[9 + 2 * r]));
            B3.u[r] = pack_rtz(__builtin_amdgcn_exp2f(st1[2 * r]),
                               __builtin_amdgcn_exp2f(st1[2 * r + 1]));
            B4.u[r] = pack_rtz(__builtin_amdgcn_exp2f(st1[8 + 2 * r]),
                               __builtin_amdgcn_exp2f(st1[9 + 2 * r]));
        }

        // O^T += V'^T x P^T (ones-row at m=16 accumulates l into acc[8])
        acc = __builtin_amdgcn_mfma_f32_32x32x16_f16(va0, B1.v, acc, 0, 0, 0);
        acc = __builtin_amdgcn_mfma_f32_32x32x16_f16(va1, B2.v, acc, 0, 0, 0);
        acc = __builtin_amdgcn_mfma_f32_32x32x16_f16(va2, B3.v, acc, 0, 0, 0);
        acc = __builtin_amdgcn_mfma_f32_32x32x16_f16(va3, B4.v, acc, 0, 0, 0);

        // V operands dead: load next chunk in-place
        if (it + 1 < NIT) {
            pv += 2048;
            va0 = *(const f16x8*)(pv);
            va1 = *(const f16x8*)(pv + 512);
            va2 = *(const f16x8*)(pv + 1024);
            va3 = *(const f16x8*)(pv + 1536);
        }
    }

    // l lives in acc[8] of the h=0 half (row 16); h=1 half's acc[8] is 0
    const float l = acc[8] + __shfl_xor(acc[8], 32, 64);
    const float inv = 1.f / l;
    const int b = bh >> 3, head = bh & 7;
    f16* op = og + ((size_t)b * Ss + qbase + q31) * Ee + head * HSs;
    uint2 lo = { pack_rne(acc[0] * inv, acc[1] * inv), pack_rne(acc[2] * inv, acc[3] * inv) };
    uint2 hi = { pack_rne(acc[4] * inv, acc[5] * inv), pack_rne(acc[6] * inv, acc[7] * inv) };
    *(uint2*)(op + 4 * h)     = lo;
    *(uint2*)(op + 8 + 4 * h) = hi;
}

// ---------------------------------------------------------------------------
// Kernel C: output projection. 32-row tiles, grid 512, 4 waves (one channel
// group each). O tile staged via LDS coalesced; Wp f16 (L1-hot); fp32 out.
// ---------------------------------------------------------------------------
__global__ __launch_bounds__(256) void proj_kernel(
    const f16* __restrict__ oh, const f16* __restrict__ wph,
    const float* __restrict__ bp, float* __restrict__ out)
{
    constexpr int LDW = 136;
    __shared__ __align__(16) f16 Os[32 * LDW];    // 8.7 KB
    const int rowbase = blockIdx.x * 32;

    for (int idx = threadIdx.x; idx < 512; idx += 256) {
        const int r = idx >> 4, cp = idx & 15;
        *(f16x8*)&Os[r * LDW + cp * 8] =
            *(const f16x8*)(oh + (size_t)(rowbase + r) * Ee + cp * 8);
    }
    __syncthreads();

    const int wv_ = threadIdx.x >> 6, lane = threadIdx.x & 63;
    const int h = lane >> 5, n31 = lane & 31;

    f16x8 A[8];
#pragma unroll
    for (int t = 0; t < 8; ++t)
        A[t] = *(const f16x8*)&Os[n31 * LDW + 16 * t + 8 * h];

    const int e = wv_ * 32 + n31;
    const f16* wr = wph + (size_t)e * Ee + 8 * h;
    f32x16 acc = {};
#pragma unroll
    for (int t = 0; t < 8; ++t)
        acc = __builtin_amdgcn_mfma_f32_32x32x16_f16(A[t], *(const f16x8*)(wr + 16 * t), acc, 0, 0, 0);

    const float bias = bp[e];
#pragma unroll
    for (int r = 0; r < 16; ++r) {
        const int R = rowbase + (r & 3) + 8 * (r >> 2) + 4 * h;
        out[(size_t)R * Ee + e] = acc[r] + bias;
    }
}

// ---------------------------------------------------------------------------
extern "C" void kernel_launch(void* const* d_in, const int* in_sizes, int n_in,
                              void* d_out, int out_size, void* d_ws, size_t ws_size,
                              hipStream_t stream)
{
    const float* x  = (const float*)d_in[0];
    const float* Wk = (const float*)d_in[1];
    const float* Wq = (const float*)d_in[2];
    const float* Wv = (const float*)d_in[3];
    const float* Wp = (const float*)d_in[4];
    const float* bp = (const float*)d_in[5];
    float* out = (float*)d_out;

    f16* ws = (f16*)d_ws;
    f16* qh = ws;                            // 2M halves
    f16* kh = ws + (size_t)QKVSZ;            // 2M
    f16* vh = ws + (size_t)2 * QKVSZ;        // 4M (A-frag order + pad rows, permuted k-slots)
    f16* oh = ws + (size_t)4 * QKVSZ;        // 2M
    f16* wh = ws + (size_t)5 * QKVSZ;        // 64K: wq|wk|wv|wp

    prep_w<<<64, 256, 0, stream>>>(Wq, Wk, Wv, Wp, wh);
    qkv_kernel<<<Bb * Ss / 32, 256, 0, stream>>>(x, wh, qh, kh, vh);
    attn_kernel<<<Bb * Hh * (Ss / 32), 64, 0, stream>>>(qh, kh, vh, oh);
    proj_kernel<<<Bb * Ss / 32, 256, 0, stream>>>(oh, wh + 49152, bp, out);
}

// Round 2
// 133.858 us; speedup vs baseline: 1.0225x; 1.0034x over previous
//
#include <hip/hip_runtime.h>
#include <hip/hip_bf16.h>

// Problem constants
constexpr int Bb  = 8;
constexpr int Ss  = 2048;
constexpr int Ee  = 128;
constexpr int Hh  = 8;
constexpr int HSs = 16;
constexpr int QKVSZ = Bb * Hh * Ss * HSs;  // 2,097,152 elements per tensor

typedef _Float16 f16;
typedef __attribute__((ext_vector_type(8)))  _Float16 f16x8;   // 8 f16 = 4 VGPRs
typedef __attribute__((ext_vector_type(16))) float f32x16;

constexpr float QSCALE = 5.770780163555854f;  // 4 * log2(e); folded into stored k

// RTZ packed fp32x2 -> fp16x2
__device__ __forceinline__ unsigned pack_rtz(float lo, float hi) {
    union { __fp16 __attribute__((ext_vector_type(2))) h; unsigned u; } c;
    c.h = __builtin_amdgcn_cvt_pkrtz(lo, hi);
    return c.u;
}
// RNE pair pack
__device__ __forceinline__ unsigned pack_rne(float lo, float hi) {
    union { __attribute__((ext_vector_type(2))) _Float16 h; unsigned u; } c;
    c.h[0] = (f16)lo; c.h[1] = (f16)hi;
    return c.u;
}

// max of 16 floats, max3-friendly groupings (ISel fuses fmax(fmax(a,b),c) -> v_max3_f32)
__device__ __forceinline__ float vmax16(const f32x16& v) {
    float a = fmaxf(fmaxf(v[0],  v[1]),  v[2]);
    float b = fmaxf(fmaxf(v[3],  v[4]),  v[5]);
    float c = fmaxf(fmaxf(v[6],  v[7]),  v[8]);
    float d = fmaxf(fmaxf(v[9],  v[10]), v[11]);
    float e = fmaxf(fmaxf(v[12], v[13]), v[14]);
    float g = fmaxf(fmaxf(a, b), c);
    float h = fmaxf(fmaxf(d, e), v[15]);
    return fmaxf(g, h);
}

// fp32x8 -> f16x8 (RNE) from two float4s
__device__ __forceinline__ f16x8 cvt8(const float4& w0, const float4& w1) {
    union { f16x8 v; unsigned u[4]; } wf;
    wf.u[0] = pack_rne(w0.x, w0.y); wf.u[1] = pack_rne(w0.z, w0.w);
    wf.u[2] = pack_rne(w1.x, w1.y); wf.u[3] = pack_rne(w1.z, w1.w);
    return wf.v;
}

// ---------------------------------------------------------------------------
// Kernel A: FUSED Q/K/V projection, inline fp32->f16 W conversion (L2-hot,
// no prep kernel). Grid 512, 4 waves. X staged fp32->f16 via LDS ONCE,
// A-frags loaded once, then 3 x 8 MFMA (q,k,v) reusing them.
// k scaled by QSCALE. v written in A-FRAG ORDER with the key-slot PERMUTATION
// matching the QK^T C-layout, so attn's P feeds PV with NO cross-lane exchange:
//   in-chunk key p = 4h' + a + 8b  ->  va-group p>>4, lane-half h'=(p>>2)&1,
//   element j = 4*((p>>3)&1) + (p&3).
// Pad rows m=16..31 (m==16 -> 1.0 ones-row for the l-accumulator trick).
// 32x32x16 layouts: A[m=lane&31][k=8h+j], B[k=8h+j][n=lane&31],
// C/D[row=(r&3)+8(r>>2)+4h][col=lane&31].
// ---------------------------------------------------------------------------
__global__ __launch_bounds__(256) void qkv_kernel(
    const float* __restrict__ x,
    const float* __restrict__ Wq, const float* __restrict__ Wk,
    const float* __restrict__ Wv,
    f16* __restrict__ qo, f16* __restrict__ ko, f16* __restrict__ vo)
{
    constexpr int LDW = 136;                      // padded row (f16), b128-aligned
    __shared__ __align__(16) f16 Xs[32 * LDW];    // 8.7 KB

    const int rowbase = blockIdx.x * 32;

    // stage X tile (32 x 128) fp32 -> f16, coalesced float4 reads (ONCE)
    for (int idx = threadIdx.x; idx < 32 * 32; idx += 256) {
        const int r = idx >> 5, cp = idx & 31;
        float4 v = *(const float4*)(x + (size_t)(rowbase + r) * Ee + cp * 4);
        union { f16 h[4]; uint2 u; } cv;
        cv.h[0] = (f16)v.x; cv.h[1] = (f16)v.y; cv.h[2] = (f16)v.z; cv.h[3] = (f16)v.w;
        *(uint2*)&Xs[r * LDW + cp * 4] = cv.u;
    }
    __syncthreads();

    const int wv_ = threadIdx.x >> 6, lane = threadIdx.x & 63;
    const int h = lane >> 5, n31 = lane & 31;

    f16x8 A[8];
#pragma unroll
    for (int t = 0; t < 8; ++t)
        A[t] = *(const f16x8*)&Xs[n31 * LDW + 16 * t + 8 * h];

    const int c = wv_ * 32 + n31;                 // channel 0..127 = head*16+d
    const int b = rowbase >> 11;
    const int s0 = rowbase & 2047;
    const int head = c >> 4, d = c & 15;
    const int bh = b * Hh + head;
    const int it = s0 >> 6, g0 = (s0 >> 4) & 3;

#pragma unroll
    for (int mat = 0; mat < 3; ++mat) {
        const float* W = (mat == 0) ? Wq : (mat == 1) ? Wk : Wv;
        const float* wr32 = W + (size_t)c * Ee + 8 * h;
        f32x16 acc = {};
#pragma unroll
        for (int t = 0; t < 8; ++t) {
            float4 w0 = *(const float4*)(wr32 + 16 * t);
            float4 w1 = *(const float4*)(wr32 + 16 * t + 4);
            acc = __builtin_amdgcn_mfma_f32_32x32x16_f16(A[t], cvt8(w0, w1), acc, 0, 0, 0);
        }

        if (mat < 2) {
            f16* dst = (mat == 0) ? qo : ko;
            const float scale = (mat == 1) ? QSCALE : 1.f;
#pragma unroll
            for (int r = 0; r < 16; ++r) {
                const int s = s0 + (r & 3) + 8 * (r >> 2) + 4 * h;
                dst[((size_t)bh * Ss + s) * HSs + d] = (f16)(acc[r] * scale);
            }
        } else {
            f16* vb = vo + (size_t)bh * 65536 + it * 2048;
#pragma unroll
            for (int rq = 0; rq < 4; ++rq) {
                union { f16 hv[4]; uint2 u; } pk4;
#pragma unroll
                for (int i = 0; i < 4; ++i) pk4.hv[i] = (f16)acc[4 * rq + i];
                // permuted k-slot placement: h' = h, b' = rq&1, j = 4*b' + a
                *(uint2*)(vb + (g0 + (rq >> 1)) * 512 + (d + 32 * h) * 8 + 4 * (rq & 1)) = pk4.u;
            }
        }
    }

    // pad rows m=16..31 for this block's two 16-key groups, all 8 heads:
    // m==16 -> 1.0 (l-accumulator row), else 0. All k-slots equal -> permutation-safe.
    for (int i = threadIdx.x; i < 512; i += 256) {
        const int gp = i >> 8, hd = (i >> 5) & 7, cc = i & 31;
        const int lanep = (cc < 16) ? 16 + cc : 32 + cc;
        const unsigned one2 = 0x3C003C00u;
        uint4 val = ((cc & 15) == 0) ? (uint4){one2, one2, one2, one2}
                                     : (uint4){0, 0, 0, 0};
        *(uint4*)(vo + (size_t)(b * Hh + hd) * 65536 + it * 2048
                  + (g0 + gp) * 512 + lanep * 8) = val;
    }
}

// ---------------------------------------------------------------------------
// Kernel B: FUSED flash attention + output projection. 512 blocks x 8 waves;
// wave = one head, block = all 8 heads of one (batch, 32-query) tile, so the
// block can concat heads in LDS and do the output projection in-kernel.
//   - attention loop: NO LDS, NO BARRIERS, NO CROSS-LANE P exchange
//     (V key-slot permutation makes B1..B4 register renames of exp(st));
//     running max folded into QK^T C-operand (cinit = -m); deferred rescale
//     THR=8 via wave-uniform __any; next-chunk operands loaded in place.
//   - epilogue: normalized O fragment -> LDS tile [32 x 136]; one barrier;
//     waves 0..3 do proj (K=128, 8 MFMA) with inline fp32->f16 Wp cvt,
//     fp32 + bias stores.
// Occupancy: 2 blocks/CU = 16 waves/CU (launch_bounds caps VGPR at 128).
// XCD swizzle: b = blk&7 -> each batch's K/V (1.5 MB) pinned to one XCD L2.
// ---------------------------------------------------------------------------
__global__ __launch_bounds__(512, 4) void attn_kernel(
    const f16* __restrict__ qg, const f16* __restrict__ kg,
    const f16* __restrict__ vg, const float* __restrict__ wp32,
    const float* __restrict__ bp, float* __restrict__ out)
{
    constexpr int LDW = 136;
    __shared__ __align__(16) f16 Os[32 * LDW];    // 8.7 KB

    const int b    = blockIdx.x & 7;               // XCD-local batches
    const int qblk = blockIdx.x >> 3;
    const int wid  = threadIdx.x >> 6;             // head
    const int lane = threadIdx.x & 63;
    const int h    = lane >> 5;
    const int q31  = lane & 31;
    const int qbase = qblk * 32;
    const int bh   = b * Hh + wid;

    // Q B-frag (QSCALE folded into k)
    const f16x8 qf = *(const f16x8*)(qg + ((size_t)bh * Ss + qbase + q31) * HSs + 8 * h);

    // per-lane streaming pointers (16B/lane contiguous, coalesced per wave)
    const f16* pk = kg + (size_t)bh * Ss * HSs + q31 * 16 + 8 * h;
    const f16* pv = vg + (size_t)bh * 65536 + lane * 8;

    // current-chunk operands
    f16x8 ka0 = *(const f16x8*)pk;
    f16x8 ka1 = *(const f16x8*)(pk + 512);
    f16x8 va0 = *(const f16x8*)(pv);
    f16x8 va1 = *(const f16x8*)(pv + 512);
    f16x8 va2 = *(const f16x8*)(pv + 1024);
    f16x8 va3 = *(const f16x8*)(pv + 1536);

    f32x16 acc = {};
    f32x16 cinit = {};                 // broadcast -m; st = s - m straight from MFMA

    constexpr int NIT = Ss / 64;
    for (int it = 0; it < NIT; ++it) {
        // S^T - m = K x Q^T + cinit for key groups 0..31, 32..63
        f32x16 st0 = __builtin_amdgcn_mfma_f32_32x32x16_f16(ka0, qf, cinit, 0, 0, 0);
        f32x16 st1 = __builtin_amdgcn_mfma_f32_32x32x16_f16(ka1, qf, cinit, 0, 0, 0);

        // K operands dead: load next chunk in-place (used next iteration)
        if (it + 1 < NIT) {
            pk += 1024;
            ka0 = *(const f16x8*)pk;
            ka1 = *(const f16x8*)(pk + 512);
        }

        // chunk max relative to m (max3 tree + one xor32)
        float mx = fmaxf(vmax16(st0), vmax16(st1));
        mx = fmaxf(mx, __shfl_xor(mx, 32, 64));

        // deferred rescale: only when some query grew past m + 8
        if (__any(mx > 8.f)) {
            const float delta = fmaxf(mx, 0.f);
            const float corr  = __builtin_amdgcn_exp2f(-delta);
#pragma unroll
            for (int r = 0; r < 9; ++r) acc[r] *= corr;   // d<16 regs + l in acc[8]
#pragma unroll
            for (int t = 0; t < 16; ++t) { st0[t] -= delta; st1[t] -= delta; }
#pragma unroll
            for (int r = 0; r < 16; ++r) cinit[r] -= delta;
        }

        // p = exp2(st) packed to f16; key-slot permutation => direct renames
        union { unsigned u[4]; f16x8 v; } B1, B2, B3, B4;
#pragma unroll
        for (int r = 0; r < 4; ++r) {
            B1.u[r] = pack_rtz(__builtin_amdgcn_exp2f(st0[2 * r]),
                               __builtin_amdgcn_exp2f(st0[2 * r + 1]));
            B2.u[r] = pack_rtz(__builtin_amdgcn_exp2f(st0[8 + 2 * r]),
                               __builtin_amdgcn_exp2f(st0[9 + 2 * r]));
            B3.u[r] = pack_rtz(__builtin_amdgcn_exp2f(st1[2 * r]),
                               __builtin_amdgcn_exp2f(st1[2 * r + 1]));
            B4.u[r] = pack_rtz(__builtin_amdgcn_exp2f(st1[8 + 2 * r]),
                               __builtin_amdgcn_exp2f(st1[9 + 2 * r]));
        }

        // O^T += V'^T x P^T (ones-row at m=16 accumulates l into acc[8])
        acc = __builtin_amdgcn_mfma_f32_32x32x16_f16(va0, B1.v, acc, 0, 0, 0);
        acc = __builtin_amdgcn_mfma_f32_32x32x16_f16(va1, B2.v, acc, 0, 0, 0);
        acc = __builtin_amdgcn_mfma_f32_32x32x16_f16(va2, B3.v, acc, 0, 0, 0);
        acc = __builtin_amdgcn_mfma_f32_32x32x16_f16(va3, B4.v, acc, 0, 0, 0);

        // V operands dead: load next chunk in-place
        if (it + 1 < NIT) {
            pv += 2048;
            va0 = *(const f16x8*)(pv);
            va1 = *(const f16x8*)(pv + 512);
            va2 = *(const f16x8*)(pv + 1024);
            va3 = *(const f16x8*)(pv + 1536);
        }
    }

    // l lives in acc[8] of the h=0 half (row 16); h=1 half's acc[8] is 0
    const float l = acc[8] + __shfl_xor(acc[8], 32, 64);
    const float inv = 1.f / l;

    // normalized O fragment (head's 8 channels for query q31) -> LDS tile
    f16* orow = &Os[q31 * LDW + wid * HSs + 4 * h];
    uint2 lo = { pack_rne(acc[0] * inv, acc[1] * inv), pack_rne(acc[2] * inv, acc[3] * inv) };
    uint2 hi = { pack_rne(acc[4] * inv, acc[5] * inv), pack_rne(acc[6] * inv, acc[7] * inv) };
    *(uint2*)(orow)     = lo;
    *(uint2*)(orow + 8) = hi;
    __syncthreads();

    if (wid >= 4) return;

    // ---- output projection: waves 0..3, one 32-channel group each ----
    f16x8 A[8];
#pragma unroll
    for (int t = 0; t < 8; ++t)
        A[t] = *(const f16x8*)&Os[q31 * LDW + 16 * t + 8 * h];

    const int e = wid * 32 + q31;
    const float* wr32 = wp32 + (size_t)e * Ee + 8 * h;
    f32x16 acc2 = {};
#pragma unroll
    for (int t = 0; t < 8; ++t) {
        float4 w0 = *(const float4*)(wr32 + 16 * t);
        float4 w1 = *(const float4*)(wr32 + 16 * t + 4);
        acc2 = __builtin_amdgcn_mfma_f32_32x32x16_f16(A[t], cvt8(w0, w1), acc2, 0, 0, 0);
    }

    const float bias = bp[e];
#pragma unroll
    for (int r = 0; r < 16; ++r) {
        const int R = qbase + (r & 3) + 8 * (r >> 2) + 4 * h;
        out[((size_t)b * Ss + R) * Ee + e] = acc2[r] + bias;
    }
}

// ---------------------------------------------------------------------------
extern "C" void kernel_launch(void* const* d_in, const int* in_sizes, int n_in,
                              void* d_out, int out_size, void* d_ws, size_t ws_size,
                              hipStream_t stream)
{
    const float* x  = (const float*)d_in[0];
    const float* Wk = (const float*)d_in[1];
    const float* Wq = (const float*)d_in[2];
    const float* Wv = (const float*)d_in[3];
    const float* Wp = (const float*)d_in[4];
    const float* bp = (const float*)d_in[5];
    float* out = (float*)d_out;

    f16* ws = (f16*)d_ws;
    f16* qh = ws;                            // 2M halves
    f16* kh = ws + (size_t)QKVSZ;            // 2M
    f16* vh = ws + (size_t)2 * QKVSZ;        // 4M (A-frag order + pad rows, permuted k-slots)

    qkv_kernel<<<Bb * Ss / 32, 256, 0, stream>>>(x, Wq, Wk, Wv, qh, kh, vh);
    attn_kernel<<<Bb * Ss / 32, 512, 0, stream>>>(qh, kh, vh, Wp, bp, out);
}

// Round 3
// 132.872 us; speedup vs baseline: 1.0301x; 1.0074x over previous
//
#include <hip/hip_runtime.h>
#include <hip/hip_bf16.h>

// Problem constants
constexpr int Bb  = 8;
constexpr int Ss  = 2048;
constexpr int Ee  = 128;
constexpr int Hh  = 8;
constexpr int HSs = 16;
constexpr int QKVSZ = Bb * Hh * Ss * HSs;  // 2,097,152 elements per tensor

typedef _Float16 f16;
typedef __attribute__((ext_vector_type(8)))  _Float16 f16x8;   // 8 f16 = 4 VGPRs
typedef __attribute__((ext_vector_type(16))) float f32x16;

constexpr float QSCALE = 5.770780163555854f;  // 4 * log2(e); folded into stored k

// RTZ packed fp32x2 -> fp16x2
__device__ __forceinline__ unsigned pack_rtz(float lo, float hi) {
    union { __fp16 __attribute__((ext_vector_type(2))) h; unsigned u; } c;
    c.h = __builtin_amdgcn_cvt_pkrtz(lo, hi);
    return c.u;
}
// RNE pair pack
__device__ __forceinline__ unsigned pack_rne(float lo, float hi) {
    union { __attribute__((ext_vector_type(2))) _Float16 h; unsigned u; } c;
    c.h[0] = (f16)lo; c.h[1] = (f16)hi;
    return c.u;
}

// max of 16 floats, max3-friendly groupings (ISel fuses fmax(fmax(a,b),c) -> v_max3_f32)
__device__ __forceinline__ float vmax16(const f32x16& v) {
    float a = fmaxf(fmaxf(v[0],  v[1]),  v[2]);
    float b = fmaxf(fmaxf(v[3],  v[4]),  v[5]);
    float c = fmaxf(fmaxf(v[6],  v[7]),  v[8]);
    float d = fmaxf(fmaxf(v[9],  v[10]), v[11]);
    float e = fmaxf(fmaxf(v[12], v[13]), v[14]);
    float g = fmaxf(fmaxf(a, b), c);
    float h = fmaxf(fmaxf(d, e), v[15]);
    return fmaxf(g, h);
}

// fp32x8 -> f16x8 (RNE) from two float4s
__device__ __forceinline__ f16x8 cvt8(const float4& w0, const float4& w1) {
    union { f16x8 v; unsigned u[4]; } wf;
    wf.u[0] = pack_rne(w0.x, w0.y); wf.u[1] = pack_rne(w0.z, w0.w);
    wf.u[2] = pack_rne(w1.x, w1.y); wf.u[3] = pack_rne(w1.z, w1.w);
    return wf.v;
}

// ---------------------------------------------------------------------------
// Kernel A: FUSED Q/K/V projection, 8 waves (512 thr), inline fp32->f16 W cvt.
// X staged fp32->f16 via LDS ONCE; the same per-lane 16B fragment serves as
// B-operand (waves 0-3, q/k, SWAPPED operand order) and A-operand (waves 4-7,
// v, original order) -- A and B per-lane layouts are identical.
//   waves 0-3 (wid=0..3): Q then K for channel group wid, C[c][s] layout ->
//     channels in regs, rows in lanes -> uint2 (4 x f16 consecutive d) stores.
//     quad rq of acc: c = 32*wid + 8*rq + 4h + i, s = s0 + n31.
//   waves 4-7: V group wid-4, original order C[s][c]; v written in A-FRAG
//     ORDER with the key-slot PERMUTATION matching the QK^T C-layout:
//     in-chunk key p = 4h' + a + 8b' -> va-group p>>4, lane-half h'=(p>>2)&1,
//     element j = 4*((p>>3)&1) + (p&3). Plus pad rows m=16..31 (m==16 -> 1.0
//     ones-row for the l-accumulator trick).
// 32x32x16 layouts: A[m=lane&31][k=8h+j], B[k=8h+j][n=lane&31],
// C/D[row=(r&3)+8(r>>2)+4h][col=lane&31].
// ---------------------------------------------------------------------------
__global__ __launch_bounds__(512, 4) void qkv_kernel(
    const float* __restrict__ x,
    const float* __restrict__ Wq, const float* __restrict__ Wk,
    const float* __restrict__ Wv,
    f16* __restrict__ qo, f16* __restrict__ ko, f16* __restrict__ vo)
{
    constexpr int LDW = 136;                      // padded row (f16), b128-aligned
    __shared__ __align__(16) f16 Xs[32 * LDW];    // 8.7 KB

    const int rowbase = blockIdx.x * 32;

    // stage X tile (32 x 128) fp32 -> f16, coalesced float4 reads (ONCE)
    for (int idx = threadIdx.x; idx < 32 * 32; idx += 512) {
        const int r = idx >> 5, cp = idx & 31;
        float4 v = *(const float4*)(x + (size_t)(rowbase + r) * Ee + cp * 4);
        union { f16 h[4]; uint2 u; } cv;
        cv.h[0] = (f16)v.x; cv.h[1] = (f16)v.y; cv.h[2] = (f16)v.z; cv.h[3] = (f16)v.w;
        *(uint2*)&Xs[r * LDW + cp * 4] = cv.u;
    }
    __syncthreads();

    const int wid = threadIdx.x >> 6, lane = threadIdx.x & 63;
    const int h = lane >> 5, n31 = lane & 31;

    // per-lane 16B X fragments (same bytes serve as A- or B-operand)
    f16x8 Xf[8];
#pragma unroll
    for (int t = 0; t < 8; ++t)
        Xf[t] = *(const f16x8*)&Xs[n31 * LDW + 16 * t + 8 * h];

    const int b = rowbase >> 11;
    const int s0 = rowbase & 2047;

    if (wid < 4) {
        // ---- Q and K, swapped operands: C[c][s], channels in regs ----
        const int s = s0 + n31;
#pragma unroll
        for (int mat = 0; mat < 2; ++mat) {
            const float* W = (mat == 0) ? Wq : Wk;
            const float* wr32 = W + (size_t)(wid * 32 + n31) * Ee + 8 * h;
            f32x16 acc = {};
#pragma unroll
            for (int t = 0; t < 8; ++t) {
                float4 w0 = *(const float4*)(wr32 + 16 * t);
                float4 w1 = *(const float4*)(wr32 + 16 * t + 4);
                acc = __builtin_amdgcn_mfma_f32_32x32x16_f16(cvt8(w0, w1), Xf[t], acc, 0, 0, 0);
            }
            f16* dst = (mat == 0) ? qo : ko;
            const float scale = (mat == 1) ? QSCALE : 1.f;
#pragma unroll
            for (int rq = 0; rq < 4; ++rq) {
                const int cbase = wid * 32 + 8 * rq + 4 * h;   // 4 consecutive c
                const int head = cbase >> 4, dbase = cbase & 15;
                union { f16 hv[4]; uint2 u; } pk4;
#pragma unroll
                for (int i = 0; i < 4; ++i) pk4.hv[i] = (f16)(acc[4 * rq + i] * scale);
                *(uint2*)(dst + ((size_t)(b * Hh + head) * Ss + s) * HSs + dbase) = pk4.u;
            }
        }
    } else {
        // ---- V, original order: C[s][c], key-slots in regs ----
        const int g = wid - 4;
        const int c = g * 32 + n31;               // channel = head*16 + d
        const int head = c >> 4, d = c & 15;
        const int bh = b * Hh + head;
        const int it = s0 >> 6, g0 = (s0 >> 4) & 3;
        const float* wr32 = Wv + (size_t)c * Ee + 8 * h;
        f32x16 acc = {};
#pragma unroll
        for (int t = 0; t < 8; ++t) {
            float4 w0 = *(const float4*)(wr32 + 16 * t);
            float4 w1 = *(const float4*)(wr32 + 16 * t + 4);
            acc = __builtin_amdgcn_mfma_f32_32x32x16_f16(Xf[t], cvt8(w0, w1), acc, 0, 0, 0);
        }
        f16* vb = vo + (size_t)bh * 65536 + it * 2048;
#pragma unroll
        for (int rq = 0; rq < 4; ++rq) {
            union { f16 hv[4]; uint2 u; } pk4;
#pragma unroll
            for (int i = 0; i < 4; ++i) pk4.hv[i] = (f16)acc[4 * rq + i];
            // permuted k-slot placement: h' = h, b' = rq&1, j = 4*b' + a
            *(uint2*)(vb + (g0 + (rq >> 1)) * 512 + (d + 32 * h) * 8 + 4 * (rq & 1)) = pk4.u;
        }

        // pad rows m=16..31 for this block's two 16-key groups, all 8 heads:
        // m==16 -> 1.0 (l-accumulator row), else 0. All k-slots equal.
        for (int i = threadIdx.x - 256; i < 512; i += 256) {
            const int gp = i >> 8, hd = (i >> 5) & 7, cc = i & 31;
            const int lanep = (cc < 16) ? 16 + cc : 32 + cc;
            const unsigned one2 = 0x3C003C00u;
            uint4 val = ((cc & 15) == 0) ? (uint4){one2, one2, one2, one2}
                                         : (uint4){0, 0, 0, 0};
            *(uint4*)(vo + (size_t)(b * Hh + hd) * 65536 + it * 2048
                      + (g0 + gp) * 512 + lanep * 8) = val;
        }
    }
}

// ---------------------------------------------------------------------------
// Kernel B: FUSED flash attention + output projection. 512 blocks x 8 waves;
// wave = one head, block = all 8 heads of one (batch, 32-query) tile, so the
// block can concat heads in LDS and do the output projection in-kernel.
//   - attention loop: NO LDS, NO BARRIERS, NO CROSS-LANE P exchange
//     (V key-slot permutation makes B1..B4 register renames of exp(st));
//     running max folded into QK^T C-operand (cinit = -m); deferred rescale
//     THR=8 via wave-uniform __any; next-chunk operands loaded in place;
//     s_setprio(1) around the PV MFMA cluster (T5).
//   - epilogue: normalized O fragment -> LDS tile [32 x 136]; one barrier;
//     waves 0..3 do proj (K=128, 8 MFMA) with inline fp32->f16 Wp cvt,
//     fp32 + bias stores.
// XCD swizzle: b = blk&7 -> each batch's K/V (1.5 MB) pinned to one XCD L2.
// ---------------------------------------------------------------------------
__global__ __launch_bounds__(512, 4) void attn_kernel(
    const f16* __restrict__ qg, const f16* __restrict__ kg,
    const f16* __restrict__ vg, const float* __restrict__ wp32,
    const float* __restrict__ bp, float* __restrict__ out)
{
    constexpr int LDW = 136;
    __shared__ __align__(16) f16 Os[32 * LDW];    // 8.7 KB

    const int b    = blockIdx.x & 7;               // XCD-local batches
    const int qblk = blockIdx.x >> 3;
    const int wid  = threadIdx.x >> 6;             // head
    const int lane = threadIdx.x & 63;
    const int h    = lane >> 5;
    const int q31  = lane & 31;
    const int qbase = qblk * 32;
    const int bh   = b * Hh + wid;

    // Q B-frag (QSCALE folded into k)
    const f16x8 qf = *(const f16x8*)(qg + ((size_t)bh * Ss + qbase + q31) * HSs + 8 * h);

    // per-lane streaming pointers (16B/lane contiguous, coalesced per wave)
    const f16* pk = kg + (size_t)bh * Ss * HSs + q31 * 16 + 8 * h;
    const f16* pv = vg + (size_t)bh * 65536 + lane * 8;

    // current-chunk operands
    f16x8 ka0 = *(const f16x8*)pk;
    f16x8 ka1 = *(const f16x8*)(pk + 512);
    f16x8 va0 = *(const f16x8*)(pv);
    f16x8 va1 = *(const f16x8*)(pv + 512);
    f16x8 va2 = *(const f16x8*)(pv + 1024);
    f16x8 va3 = *(const f16x8*)(pv + 1536);

    f32x16 acc = {};
    f32x16 cinit = {};                 // broadcast -m; st = s - m straight from MFMA

    constexpr int NIT = Ss / 64;
    for (int it = 0; it < NIT; ++it) {
        // S^T - m = K x Q^T + cinit for key groups 0..31, 32..63
        f32x16 st0 = __builtin_amdgcn_mfma_f32_32x32x16_f16(ka0, qf, cinit, 0, 0, 0);
        f32x16 st1 = __builtin_amdgcn_mfma_f32_32x32x16_f16(ka1, qf, cinit, 0, 0, 0);

        // K operands dead: load next chunk in-place (used next iteration)
        if (it + 1 < NIT) {
            pk += 1024;
            ka0 = *(const f16x8*)pk;
            ka1 = *(const f16x8*)(pk + 512);
        }

        // chunk max relative to m (max3 tree + one xor32)
        float mx = fmaxf(vmax16(st0), vmax16(st1));
        mx = fmaxf(mx, __shfl_xor(mx, 32, 64));

        // deferred rescale: only when some query grew past m + 8
        if (__any(mx > 8.f)) {
            const float delta = fmaxf(mx, 0.f);
            const float corr  = __builtin_amdgcn_exp2f(-delta);
#pragma unroll
            for (int r = 0; r < 9; ++r) acc[r] *= corr;   // d<16 regs + l in acc[8]
#pragma unroll
            for (int t = 0; t < 16; ++t) { st0[t] -= delta; st1[t] -= delta; }
#pragma unroll
            for (int r = 0; r < 16; ++r) cinit[r] -= delta;
        }

        // p = exp2(st) packed to f16; key-slot permutation => direct renames
        union { unsigned u[4]; f16x8 v; } B1, B2, B3, B4;
#pragma unroll
        for (int r = 0; r < 4; ++r) {
            B1.u[r] = pack_rtz(__builtin_amdgcn_exp2f(st0[2 * r]),
                               __builtin_amdgcn_exp2f(st0[2 * r + 1]));
            B2.u[r] = pack_rtz(__builtin_amdgcn_exp2f(st0[8 + 2 * r]),
                               __builtin_amdgcn_exp2f(st0[9 + 2 * r]));
            B3.u[r] = pack_rtz(__builtin_amdgcn_exp2f(st1[2 * r]),
                               __builtin_amdgcn_exp2f(st1[2 * r + 1]));
            B4.u[r] = pack_rtz(__builtin_amdgcn_exp2f(st1[8 + 2 * r]),
                               __builtin_amdgcn_exp2f(st1[9 + 2 * r]));
        }

        // O^T += V'^T x P^T (ones-row at m=16 accumulates l into acc[8])
        __builtin_amdgcn_s_setprio(1);
        acc = __builtin_amdgcn_mfma_f32_32x32x16_f16(va0, B1.v, acc, 0, 0, 0);
        acc = __builtin_amdgcn_mfma_f32_32x32x16_f16(va1, B2.v, acc, 0, 0, 0);
        acc = __builtin_amdgcn_mfma_f32_32x32x16_f16(va2, B3.v, acc, 0, 0, 0);
        acc = __builtin_amdgcn_mfma_f32_32x32x16_f16(va3, B4.v, acc, 0, 0, 0);
        __builtin_amdgcn_s_setprio(0);

        // V operands dead: load next chunk in-place
        if (it + 1 < NIT) {
            pv += 2048;
            va0 = *(const f16x8*)(pv);
            va1 = *(const f16x8*)(pv + 512);
            va2 = *(const f16x8*)(pv + 1024);
            va3 = *(const f16x8*)(pv + 1536);
        }
    }

    // l lives in acc[8] of the h=0 half (row 16); h=1 half's acc[8] is 0
    const float l = acc[8] + __shfl_xor(acc[8], 32, 64);
    const float inv = 1.f / l;

    // normalized O fragment (head's 8 channels for query q31) -> LDS tile
    f16* orow = &Os[q31 * LDW + wid * HSs + 4 * h];
    uint2 lo = { pack_rne(acc[0] * inv, acc[1] * inv), pack_rne(acc[2] * inv, acc[3] * inv) };
    uint2 hi = { pack_rne(acc[4] * inv, acc[5] * inv), pack_rne(acc[6] * inv, acc[7] * inv) };
    *(uint2*)(orow)     = lo;
    *(uint2*)(orow + 8) = hi;
    __syncthreads();

    if (wid >= 4) return;

    // ---- output projection: waves 0..3, one 32-channel group each ----
    f16x8 A[8];
#pragma unroll
    for (int t = 0; t < 8; ++t)
        A[t] = *(const f16x8*)&Os[q31 * LDW + 16 * t + 8 * h];

    const int e = wid * 32 + q31;
    const float* wr32 = wp32 + (size_t)e * Ee + 8 * h;
    f32x16 acc2 = {};
#pragma unroll
    for (int t = 0; t < 8; ++t) {
        float4 w0 = *(const float4*)(wr32 + 16 * t);
        float4 w1 = *(const float4*)(wr32 + 16 * t + 4);
        acc2 = __builtin_amdgcn_mfma_f32_32x32x16_f16(A[t], cvt8(w0, w1), acc2, 0, 0, 0);
    }

    const float bias = bp[e];
#pragma unroll
    for (int r = 0; r < 16; ++r) {
        const int R = qbase + (r & 3) + 8 * (r >> 2) + 4 * h;
        out[((size_t)b * Ss + R) * Ee + e] = acc2[r] + bias;
    }
}

// ---------------------------------------------------------------------------
extern "C" void kernel_launch(void* const* d_in, const int* in_sizes, int n_in,
                              void* d_out, int out_size, void* d_ws, size_t ws_size,
                              hipStream_t stream)
{
    const float* x  = (const float*)d_in[0];
    const float* Wk = (const float*)d_in[1];
    const float* Wq = (const float*)d_in[2];
    const float* Wv = (const float*)d_in[3];
    const float* Wp = (const float*)d_in[4];
    const float* bp = (const float*)d_in[5];
    float* out = (float*)d_out;

    f16* ws = (f16*)d_ws;
    f16* qh = ws;                            // 2M halves
    f16* kh = ws + (size_t)QKVSZ;            // 2M
    f16* vh = ws + (size_t)2 * QKVSZ;        // 4M (A-frag order + pad rows, permuted k-slots)

    qkv_kernel<<<Bb * Ss / 32, 512, 0, stream>>>(x, Wq, Wk, Wv, qh, kh, vh);
    attn_kernel<<<Bb * Ss / 32, 512, 0, stream>>>(qh, kh, vh, Wp, bp, out);
}